// Round 8
// baseline (232.926 us; speedup 1.0000x reference)
//
#include <hip/hip_runtime.h>

#define N_NODES 100000
#define N_EDGES 1600000
#define D_IN    128
#define D_OUT   32
#define RPB     16                      // rows per fine bucket
#define NB      (N_NODES / RPB)         // 6250 fine buckets
#define CROWS   2048                    // rows per coarse bucket
#define NCB     49                      // ceil(100000/2048)
#define FPC     (CROWS / RPB)           // 128 fine buckets per coarse
#define NSH     8                       // shards per coarse (by blockIdx&7)
#define CAP_A   4500                    // records per (coarse,shard) seg
#define DEPTH   48                      // LDS staging depth per coarse bin
#define CAPF    352                     // records per fine bucket
#define GRID_A  512
#define EPB_A   (N_EDGES / GRID_A)      // 3125 edges per phase-A block

typedef __attribute__((ext_vector_type(8))) short bf16x8;
typedef __attribute__((ext_vector_type(4))) float f32x4;

__device__ inline short f2bf(float f) {         // RNE float->bf16
    union { float f; unsigned u; } v; v.f = f;
    unsigned r = (v.u + 0x7FFFu + ((v.u >> 16) & 1u)) >> 16;
    return (short)r;
}
__device__ inline float bf2f(unsigned short b) {
    return __uint_as_float((unsigned)b << 16);
}

// ---------------------------------------------------------------------------
// W [128][32] fp32  ->  WbT [32][128] bf16
// ---------------------------------------------------------------------------
__global__ __launch_bounds__(256) void wconv_kernel(
    const float* __restrict__ W, short* __restrict__ WbT)
{
    const int i = blockIdx.x * 256 + threadIdx.x;
    if (i >= D_IN * D_OUT) return;
    const int k = i >> 5, c = i & 31;
    WbT[c * D_IN + k] = f2bf(W[i]);
}

// ---------------------------------------------------------------------------
// h16 = bf16(relu(input @ W)) via mfma_f32_16x16x32_bf16 (unchanged).
// ---------------------------------------------------------------------------
__global__ __launch_bounds__(256) void gemm_mfma_kernel(
    const float* __restrict__ in, const short* __restrict__ WbT,
    unsigned short* __restrict__ h16)
{
    const int wave = threadIdx.x >> 6;
    const int lane = threadIdx.x & 63;
    const int r0   = blockIdx.x * 64 + wave * 16;
    const int c16  = lane & 15;
    const int quad = lane >> 4;

    int ra = r0 + c16;
    if (ra >= N_NODES) ra = N_NODES - 1;
    const float* arow = in + (size_t)ra * D_IN;

    f32x4 acc0 = {0.f, 0.f, 0.f, 0.f};
    f32x4 acc1 = {0.f, 0.f, 0.f, 0.f};

#pragma unroll
    for (int q = 0; q < 4; ++q) {
        const float* ap = arow + q * 32 + quad * 8;
        f32x4 a0 = *(const f32x4*)(ap);
        f32x4 a1 = *(const f32x4*)(ap + 4);
        bf16x8 af;
        af[0] = f2bf(a0.x); af[1] = f2bf(a0.y); af[2] = f2bf(a0.z); af[3] = f2bf(a0.w);
        af[4] = f2bf(a1.x); af[5] = f2bf(a1.y); af[6] = f2bf(a1.z); af[7] = f2bf(a1.w);
        bf16x8 b0 = *(const bf16x8*)(WbT + (c16)      * D_IN + q * 32 + quad * 8);
        bf16x8 b1 = *(const bf16x8*)(WbT + (c16 + 16) * D_IN + q * 32 + quad * 8);
        acc0 = __builtin_amdgcn_mfma_f32_16x16x32_bf16(af, b0, acc0, 0, 0, 0);
        acc1 = __builtin_amdgcn_mfma_f32_16x16x32_bf16(af, b1, acc1, 0, 0, 0);
    }

#pragma unroll
    for (int i = 0; i < 4; ++i) {
        const int rr = r0 + quad * 4 + i;
        if (rr < N_NODES) {
            h16[(size_t)rr * D_OUT + c16]      = (unsigned short)f2bf(fmaxf(acc0[i], 0.f));
            h16[(size_t)rr * D_OUT + c16 + 16] = (unsigned short)f2bf(fmaxf(acc1[i], 0.f));
        }
    }
}

// ---------------------------------------------------------------------------
// Phase A: 49-coarse x 8-shard partition, LDS-staged, full-128B-chunk
// flushes. FLUSH IS LANE-PARALLEL this round: wave w owns bins w,w+4,...;
// lane k copies record k (2-way LDS bank aliasing = free), lane 0 bumps
// the global cursor and broadcasts via readfirstlane.
// ---------------------------------------------------------------------------
__global__ __launch_bounds__(256) void phaseA_kernel(
    const int* __restrict__ erow, const int* __restrict__ ecol,
    const int* __restrict__ etime, const float* __restrict__ dw1,
    int* __restrict__ gcur,          // NCB*NSH cursors, stride 16 ints
    uint2* __restrict__ segA)
{
    __shared__ uint2 lbin[NCB][DEPTH];   // 18.4 KB
    __shared__ int   lcnt[NCB];

    const int tid   = threadIdx.x;
    const int blk   = blockIdx.x;
    const int shard = blk & (NSH - 1);
    const int wv    = tid >> 6;          // wave 0..3
    const int ln    = tid & 63;

    if (tid < NCB) lcnt[tid] = 0;
    __syncthreads();

    const int base_e = blk * EPB_A;
    const int iters  = (EPB_A + 255) / 256;   // 13

    for (int it = 0; it < iters; ++it) {
        const int e = base_e + it * 256 + tid;
        if (e < base_e + EPB_A) {
            const int row = erow[e];
            const int cb  = row >> 11;
            uint2 p;
            p.x = (unsigned)ecol[e] | ((unsigned)(row & (CROWS - 1)) << 17);
            p.y = __float_as_uint(dw1[etime[e]]);
            const int pos = atomicAdd(&lcnt[cb], 1);
            if (pos < DEPTH) lbin[cb][pos] = p;
        }
        __syncthreads();
        // lane-parallel flush of full 16-record chunks
        for (int bin = wv; bin < NCB; bin += 4) {
            const int c  = min(lcnt[bin], DEPTH);
            const int nf = c & ~15;          // full-16 record count
            if (nf) {
                int gb = 0;
                if (ln == 0) gb = atomicAdd(&gcur[(bin * NSH + shard) * 16], nf);
                gb = __builtin_amdgcn_readfirstlane(gb);
                uint2* seg = segA + (size_t)(bin * NSH + shard) * CAP_A;
                if (ln < nf && gb + ln < CAP_A) seg[gb + ln] = lbin[bin][ln];
                const int rem = c - nf;
                uint2 t;
                if (ln < rem) t = lbin[bin][nf + ln];   // wave-lockstep: reads
                if (ln < rem) lbin[bin][ln] = t;        //   precede writes
                if (ln == 0) lcnt[bin] = rem;
            }
        }
        __syncthreads();
    }
    // drain leftovers (<16 per bin), lane-parallel
    for (int bin = wv; bin < NCB; bin += 4) {
        const int c = min(lcnt[bin], DEPTH);
        if (c) {
            int gb = 0;
            if (ln == 0) gb = atomicAdd(&gcur[(bin * NSH + shard) * 16], c);
            gb = __builtin_amdgcn_readfirstlane(gb);
            uint2* seg = segA + (size_t)(bin * NSH + shard) * CAP_A;
            if (ln < c && gb + ln < CAP_A) seg[gb + ln] = lbin[bin][ln];
        }
    }
}

// ---------------------------------------------------------------------------
// Phase B: one block per (coarse, shard) segment -> fine buckets (unchanged).
// ---------------------------------------------------------------------------
__global__ __launch_bounds__(256) void phaseB_kernel(
    const int* __restrict__ gcur, const uint2* __restrict__ segA,
    int* __restrict__ fcur,
    uint2* __restrict__ spk2)
{
    __shared__ int hist[FPC];
    __shared__ int curs[FPC];

    const int tid   = threadIdx.x;
    const int cb    = blockIdx.x >> 3;
    const int shard = blockIdx.x & 7;
    const int n     = min(gcur[(cb * NSH + shard) * 16], CAP_A);
    const uint2* seg = segA + (size_t)(cb * NSH + shard) * CAP_A;

    if (tid < FPC) hist[tid] = 0;
    __syncthreads();

    for (int i = tid; i < n; i += 256)
        atomicAdd(&hist[(seg[i].x >> 21) & 127], 1);
    __syncthreads();

    if (tid < FPC) {
        const int h  = hist[tid];
        const int fb = cb * FPC + tid;
        curs[tid] = (h && fb < NB) ? atomicAdd(&fcur[fb], h) : 0;
    }
    __syncthreads();

    for (int i = tid; i < n; i += 256) {
        const uint2 p  = seg[i];
        const int   fl = (p.x >> 21) & 127;
        const int  pos = atomicAdd(&curs[fl], 1);
        if (pos < CAPF)
            spk2[(size_t)(cb * FPC + fl) * CAPF + pos] = p;
    }
}

// ---------------------------------------------------------------------------
// Bucket reduce (unchanged from round 7).
// ---------------------------------------------------------------------------
__global__ __launch_bounds__(256) void bucket_reduce_kernel(
    const unsigned short* __restrict__ h16, const int* __restrict__ fcur,
    const uint2* __restrict__ spk2, const float* __restrict__ dw2,
    const int* __restrict__ arrive, const int* __restrict__ obs,
    float* __restrict__ out)
{
    __shared__ uint2 pk[CAPF];
    __shared__ uint2 pk2[CAPF];
    __shared__ int   bin[RPB];
    __shared__ int   start[RPB + 1];
    __shared__ int   cur[RPB];

    const int tid = threadIdx.x;
    const int b   = blockIdx.x;
    const int n   = min(fcur[b], CAPF);
    const uint2* seg = spk2 + (size_t)b * CAPF;

    if (tid < RPB) bin[tid] = 0;
    __syncthreads();

    for (int i = tid; i < n; i += 256) {
        const uint2 p = seg[i];
        pk[i] = p;
        atomicAdd(&bin[(p.x >> 17) & 15], 1);
    }
    __syncthreads();

    if (tid == 0) {
        int a = 0;
#pragma unroll
        for (int r = 0; r < RPB; ++r) { start[r] = a; cur[r] = a; a += bin[r]; }
        start[RPB] = a;
    }
    __syncthreads();

    for (int i = tid; i < n; i += 256) {
        const uint2 p = pk[i];
        pk2[atomicAdd(&cur[(p.x >> 17) & 15], 1)] = p;
    }
    __syncthreads();

    const int c = tid & 31;
    const int g = tid >> 5;
    const int T = 60 * obs[0];

#pragma unroll
    for (int rr = 0; rr < 2; ++rr) {
        const int rl  = g * 2 + rr;
        const int beg = start[rl];
        const int end = start[rl + 1];

        float acc = 0.f;
        int j = beg;
        for (; j + 4 <= end; j += 4) {
            const uint2 p0 = pk2[j];
            const uint2 p1 = pk2[j + 1];
            const uint2 p2 = pk2[j + 2];
            const uint2 p3 = pk2[j + 3];
            const float v0 = bf2f(h16[(size_t)(p0.x & 0x1FFFF) * D_OUT + c]);
            const float v1 = bf2f(h16[(size_t)(p1.x & 0x1FFFF) * D_OUT + c]);
            const float v2 = bf2f(h16[(size_t)(p2.x & 0x1FFFF) * D_OUT + c]);
            const float v3 = bf2f(h16[(size_t)(p3.x & 0x1FFFF) * D_OUT + c]);
            acc = fmaf(__uint_as_float(p0.y), v0, acc);
            acc = fmaf(__uint_as_float(p1.y), v1, acc);
            acc = fmaf(__uint_as_float(p2.y), v2, acc);
            acc = fmaf(__uint_as_float(p3.y), v3, acc);
        }
        for (; j < end; ++j) {
            const uint2 p = pk2[j];
            acc = fmaf(__uint_as_float(p.y),
                       bf2f(h16[(size_t)(p.x & 0x1FFFF) * D_OUT + c]), acc);
        }

        const int r = b * RPB + rl;
        const float sdw = dw2[T - arrive[r] - 1];
        out[(size_t)r * D_OUT + c] = acc * sdw;
    }
}

extern "C" void kernel_launch(void* const* d_in, const int* in_sizes, int n_in,
                              void* d_out, int out_size, void* d_ws, size_t ws_size,
                              hipStream_t stream)
{
    const float* input  = (const float*)d_in[0];
    const float* W      = (const float*)d_in[1];
    const float* dw1    = (const float*)d_in[2];
    const float* dw2    = (const float*)d_in[3];
    const int*   erow   = (const int*)d_in[4];
    const int*   ecol   = (const int*)d_in[5];
    const int*   etime  = (const int*)d_in[6];
    const int*   arrive = (const int*)d_in[7];
    const int*   obs    = (const int*)d_in[8];

    float* out = (float*)d_out;

    // Workspace layout (~38.2 MB), 256B-aligned chunks
    char* p = (char*)d_ws;
    unsigned short* h16 = (unsigned short*)p;                 // 6.4 MB
    p += (size_t)N_NODES * D_OUT * 2;
    p = (char*)(((size_t)p + 255) & ~(size_t)255);
    short* WbT = (short*)p;                                   // 8 KB
    p += D_IN * D_OUT * 2;
    p = (char*)(((size_t)p + 255) & ~(size_t)255);
    int* gcur = (int*)p;                                      // 25 KB
    p += (size_t)NCB * NSH * 16 * 4;
    int* fcur = (int*)p;                                      // 25 KB
    p += (size_t)NB * 4;
    p = (char*)(((size_t)p + 255) & ~(size_t)255);
    uint2* segA = (uint2*)p;                                  // 14.1 MB
    p += (size_t)NCB * NSH * CAP_A * 8;
    p = (char*)(((size_t)p + 255) & ~(size_t)255);
    uint2* spk2 = (uint2*)p;                                  // 17.6 MB

    hipMemsetAsync(gcur, 0, (size_t)(NCB * NSH * 16 + NB) * 4, stream);

    wconv_kernel<<<(D_IN * D_OUT + 255) / 256, 256, 0, stream>>>(W, WbT);
    gemm_mfma_kernel<<<(N_NODES + 63) / 64, 256, 0, stream>>>(input, WbT, h16);
    phaseA_kernel<<<GRID_A, 256, 0, stream>>>(erow, ecol, etime, dw1, gcur, segA);
    phaseB_kernel<<<NCB * NSH, 256, 0, stream>>>(gcur, segA, fcur, spk2);
    bucket_reduce_kernel<<<NB, 256, 0, stream>>>(
        h16, fcur, spk2, dw2, arrive, obs, out);
}

// Round 9
// 185.884 us; speedup vs baseline: 1.2531x; 1.2531x over previous
//
#include <hip/hip_runtime.h>

#define N_NODES 100000
#define N_EDGES 1600000
#define D_IN    128
#define D_OUT   32
#define RPB     16                      // rows per fine bucket
#define NB      (N_NODES / RPB)         // 6250 fine buckets
#define CROWS   2048                    // rows per coarse bucket
#define NCB     49                      // ceil(100000/2048)
#define FPC     (CROWS / RPB)           // 128 fine buckets per coarse
#define NSH     8                       // shards per coarse (by blockIdx&7)
#define CAP_A   4500                    // records per (coarse,shard) seg
#define DEPTH   48                      // LDS staging depth per bin (mean 16, +8s)
#define CAPF    352                     // records per fine bucket
#define GRID_A  2048                    // 8 blocks/CU
#define EPB_A   ((N_EDGES + GRID_A - 1) / GRID_A)   // 782

typedef __attribute__((ext_vector_type(8))) short bf16x8;
typedef __attribute__((ext_vector_type(4))) float f32x4;

__device__ inline short f2bf(float f) {         // RNE float->bf16
    union { float f; unsigned u; } v; v.f = f;
    unsigned r = (v.u + 0x7FFFu + ((v.u >> 16) & 1u)) >> 16;
    return (short)r;
}
__device__ inline float bf2f(unsigned short b) {
    return __uint_as_float((unsigned)b << 16);
}

// ---------------------------------------------------------------------------
// W [128][32] fp32  ->  WbT [32][128] bf16
// ---------------------------------------------------------------------------
__global__ __launch_bounds__(256) void wconv_kernel(
    const float* __restrict__ W, short* __restrict__ WbT)
{
    const int i = blockIdx.x * 256 + threadIdx.x;
    if (i >= D_IN * D_OUT) return;
    const int k = i >> 5, c = i & 31;
    WbT[c * D_IN + k] = f2bf(W[i]);
}

// ---------------------------------------------------------------------------
// h16 = bf16(relu(input @ W)) via mfma_f32_16x16x32_bf16 (unchanged).
// ---------------------------------------------------------------------------
__global__ __launch_bounds__(256) void gemm_mfma_kernel(
    const float* __restrict__ in, const short* __restrict__ WbT,
    unsigned short* __restrict__ h16)
{
    const int wave = threadIdx.x >> 6;
    const int lane = threadIdx.x & 63;
    const int r0   = blockIdx.x * 64 + wave * 16;
    const int c16  = lane & 15;
    const int quad = lane >> 4;

    int ra = r0 + c16;
    if (ra >= N_NODES) ra = N_NODES - 1;
    const float* arow = in + (size_t)ra * D_IN;

    f32x4 acc0 = {0.f, 0.f, 0.f, 0.f};
    f32x4 acc1 = {0.f, 0.f, 0.f, 0.f};

#pragma unroll
    for (int q = 0; q < 4; ++q) {
        const float* ap = arow + q * 32 + quad * 8;
        f32x4 a0 = *(const f32x4*)(ap);
        f32x4 a1 = *(const f32x4*)(ap + 4);
        bf16x8 af;
        af[0] = f2bf(a0.x); af[1] = f2bf(a0.y); af[2] = f2bf(a0.z); af[3] = f2bf(a0.w);
        af[4] = f2bf(a1.x); af[5] = f2bf(a1.y); af[6] = f2bf(a1.z); af[7] = f2bf(a1.w);
        bf16x8 b0 = *(const bf16x8*)(WbT + (c16)      * D_IN + q * 32 + quad * 8);
        bf16x8 b1 = *(const bf16x8*)(WbT + (c16 + 16) * D_IN + q * 32 + quad * 8);
        acc0 = __builtin_amdgcn_mfma_f32_16x16x32_bf16(af, b0, acc0, 0, 0, 0);
        acc1 = __builtin_amdgcn_mfma_f32_16x16x32_bf16(af, b1, acc1, 0, 0, 0);
    }

#pragma unroll
    for (int i = 0; i < 4; ++i) {
        const int rr = r0 + quad * 4 + i;
        if (rr < N_NODES) {
            h16[(size_t)rr * D_OUT + c16]      = (unsigned short)f2bf(fmaxf(acc0[i], 0.f));
            h16[(size_t)rr * D_OUT + c16 + 16] = (unsigned short)f2bf(fmaxf(acc1[i], 0.f));
        }
    }
}

// ---------------------------------------------------------------------------
// Phase A, round 9: 2048 blocks (8/CU), ~782 edges/block, SINGLE flush at
// block end. Cursor bumps for all 49 bins issue as ONE parallel vector
// atomic (threads 0..48), bases parked in LDS; copies are lane-parallel
// with no atomics. No barriers in the insertion loop.
// ---------------------------------------------------------------------------
__global__ __launch_bounds__(256) void phaseA_kernel(
    const int* __restrict__ erow, const int* __restrict__ ecol,
    const int* __restrict__ etime, const float* __restrict__ dw1,
    int* __restrict__ gcur,          // NCB*NSH cursors, stride 16 ints
    uint2* __restrict__ segA)
{
    __shared__ uint2 lbin[NCB][DEPTH];   // 18.8 KB
    __shared__ int   lcnt[NCB];
    __shared__ int   gbase[NCB];

    const int tid   = threadIdx.x;
    const int blk   = blockIdx.x;
    const int shard = blk & (NSH - 1);
    const int wv    = tid >> 6;          // wave 0..3
    const int ln    = tid & 63;

    if (tid < NCB) lcnt[tid] = 0;
    __syncthreads();

    const int e_beg = blk * EPB_A;
    const int e_end = min(e_beg + EPB_A, N_EDGES);

    for (int e = e_beg + tid; e < e_end; e += 256) {
        const int row = erow[e];
        const int cb  = row >> 11;
        uint2 p;
        p.x = (unsigned)ecol[e] | ((unsigned)(row & (CROWS - 1)) << 17);
        p.y = __float_as_uint(dw1[etime[e]]);
        const int pos = atomicAdd(&lcnt[cb], 1);
        if (pos < DEPTH) lbin[cb][pos] = p;   // overflow: +8 sigma, never
    }
    __syncthreads();

    // All 49 cursor bumps in one parallel vector atomic.
    if (tid < NCB) {
        const int c = min(lcnt[tid], DEPTH);
        gbase[tid] = atomicAdd(&gcur[(tid * NSH + shard) * 16], c);
    }
    __syncthreads();

    // Lane-parallel, atomic-free copies: wave wv owns bins wv, wv+4, ...
    for (int bin = wv; bin < NCB; bin += 4) {
        const int c  = min(lcnt[bin], DEPTH);
        const int gb = gbase[bin];
        uint2* seg = segA + (size_t)(bin * NSH + shard) * CAP_A;
        for (int k = ln; k < c; k += 64) {
            if (gb + k < CAP_A) seg[gb + k] = lbin[bin][k];
        }
    }
}

// ---------------------------------------------------------------------------
// Phase B: one block per (coarse, shard) segment -> fine buckets (unchanged).
// ---------------------------------------------------------------------------
__global__ __launch_bounds__(256) void phaseB_kernel(
    const int* __restrict__ gcur, const uint2* __restrict__ segA,
    int* __restrict__ fcur,
    uint2* __restrict__ spk2)
{
    __shared__ int hist[FPC];
    __shared__ int curs[FPC];

    const int tid   = threadIdx.x;
    const int cb    = blockIdx.x >> 3;
    const int shard = blockIdx.x & 7;
    const int n     = min(gcur[(cb * NSH + shard) * 16], CAP_A);
    const uint2* seg = segA + (size_t)(cb * NSH + shard) * CAP_A;

    if (tid < FPC) hist[tid] = 0;
    __syncthreads();

    for (int i = tid; i < n; i += 256)
        atomicAdd(&hist[(seg[i].x >> 21) & 127], 1);
    __syncthreads();

    if (tid < FPC) {
        const int h  = hist[tid];
        const int fb = cb * FPC + tid;
        curs[tid] = (h && fb < NB) ? atomicAdd(&fcur[fb], h) : 0;
    }
    __syncthreads();

    for (int i = tid; i < n; i += 256) {
        const uint2 p  = seg[i];
        const int   fl = (p.x >> 21) & 127;
        const int  pos = atomicAdd(&curs[fl], 1);
        if (pos < CAPF)
            spk2[(size_t)(cb * FPC + fl) * CAPF + pos] = p;
    }
}

// ---------------------------------------------------------------------------
// Bucket reduce (unchanged from round 7).
// ---------------------------------------------------------------------------
__global__ __launch_bounds__(256) void bucket_reduce_kernel(
    const unsigned short* __restrict__ h16, const int* __restrict__ fcur,
    const uint2* __restrict__ spk2, const float* __restrict__ dw2,
    const int* __restrict__ arrive, const int* __restrict__ obs,
    float* __restrict__ out)
{
    __shared__ uint2 pk[CAPF];
    __shared__ uint2 pk2[CAPF];
    __shared__ int   bin[RPB];
    __shared__ int   start[RPB + 1];
    __shared__ int   cur[RPB];

    const int tid = threadIdx.x;
    const int b   = blockIdx.x;
    const int n   = min(fcur[b], CAPF);
    const uint2* seg = spk2 + (size_t)b * CAPF;

    if (tid < RPB) bin[tid] = 0;
    __syncthreads();

    for (int i = tid; i < n; i += 256) {
        const uint2 p = seg[i];
        pk[i] = p;
        atomicAdd(&bin[(p.x >> 17) & 15], 1);
    }
    __syncthreads();

    if (tid == 0) {
        int a = 0;
#pragma unroll
        for (int r = 0; r < RPB; ++r) { start[r] = a; cur[r] = a; a += bin[r]; }
        start[RPB] = a;
    }
    __syncthreads();

    for (int i = tid; i < n; i += 256) {
        const uint2 p = pk[i];
        pk2[atomicAdd(&cur[(p.x >> 17) & 15], 1)] = p;
    }
    __syncthreads();

    const int c = tid & 31;
    const int g = tid >> 5;
    const int T = 60 * obs[0];

#pragma unroll
    for (int rr = 0; rr < 2; ++rr) {
        const int rl  = g * 2 + rr;
        const int beg = start[rl];
        const int end = start[rl + 1];

        float acc = 0.f;
        int j = beg;
        for (; j + 4 <= end; j += 4) {
            const uint2 p0 = pk2[j];
            const uint2 p1 = pk2[j + 1];
            const uint2 p2 = pk2[j + 2];
            const uint2 p3 = pk2[j + 3];
            const float v0 = bf2f(h16[(size_t)(p0.x & 0x1FFFF) * D_OUT + c]);
            const float v1 = bf2f(h16[(size_t)(p1.x & 0x1FFFF) * D_OUT + c]);
            const float v2 = bf2f(h16[(size_t)(p2.x & 0x1FFFF) * D_OUT + c]);
            const float v3 = bf2f(h16[(size_t)(p3.x & 0x1FFFF) * D_OUT + c]);
            acc = fmaf(__uint_as_float(p0.y), v0, acc);
            acc = fmaf(__uint_as_float(p1.y), v1, acc);
            acc = fmaf(__uint_as_float(p2.y), v2, acc);
            acc = fmaf(__uint_as_float(p3.y), v3, acc);
        }
        for (; j < end; ++j) {
            const uint2 p = pk2[j];
            acc = fmaf(__uint_as_float(p.y),
                       bf2f(h16[(size_t)(p.x & 0x1FFFF) * D_OUT + c]), acc);
        }

        const int r = b * RPB + rl;
        const float sdw = dw2[T - arrive[r] - 1];
        out[(size_t)r * D_OUT + c] = acc * sdw;
    }
}

extern "C" void kernel_launch(void* const* d_in, const int* in_sizes, int n_in,
                              void* d_out, int out_size, void* d_ws, size_t ws_size,
                              hipStream_t stream)
{
    const float* input  = (const float*)d_in[0];
    const float* W      = (const float*)d_in[1];
    const float* dw1    = (const float*)d_in[2];
    const float* dw2    = (const float*)d_in[3];
    const int*   erow   = (const int*)d_in[4];
    const int*   ecol   = (const int*)d_in[5];
    const int*   etime  = (const int*)d_in[6];
    const int*   arrive = (const int*)d_in[7];
    const int*   obs    = (const int*)d_in[8];

    float* out = (float*)d_out;

    // Workspace layout (~38.2 MB), 256B-aligned chunks
    char* p = (char*)d_ws;
    unsigned short* h16 = (unsigned short*)p;                 // 6.4 MB
    p += (size_t)N_NODES * D_OUT * 2;
    p = (char*)(((size_t)p + 255) & ~(size_t)255);
    short* WbT = (short*)p;                                   // 8 KB
    p += D_IN * D_OUT * 2;
    p = (char*)(((size_t)p + 255) & ~(size_t)255);
    int* gcur = (int*)p;                                      // 25 KB
    p += (size_t)NCB * NSH * 16 * 4;
    int* fcur = (int*)p;                                      // 25 KB
    p += (size_t)NB * 4;
    p = (char*)(((size_t)p + 255) & ~(size_t)255);
    uint2* segA = (uint2*)p;                                  // 14.1 MB
    p += (size_t)NCB * NSH * CAP_A * 8;
    p = (char*)(((size_t)p + 255) & ~(size_t)255);
    uint2* spk2 = (uint2*)p;                                  // 17.6 MB

    hipMemsetAsync(gcur, 0, (size_t)(NCB * NSH * 16 + NB) * 4, stream);

    wconv_kernel<<<(D_IN * D_OUT + 255) / 256, 256, 0, stream>>>(W, WbT);
    gemm_mfma_kernel<<<(N_NODES + 63) / 64, 256, 0, stream>>>(input, WbT, h16);
    phaseA_kernel<<<GRID_A, 256, 0, stream>>>(erow, ecol, etime, dw1, gcur, segA);
    phaseB_kernel<<<NCB * NSH, 256, 0, stream>>>(gcur, segA, fcur, spk2);
    bucket_reduce_kernel<<<NB, 256, 0, stream>>>(
        h16, fcur, spk2, dw2, arrive, obs, out);
}

// Round 10
// 184.719 us; speedup vs baseline: 1.2610x; 1.0063x over previous
//
#include <hip/hip_runtime.h>

#define N_NODES 100000
#define N_EDGES 1600000
#define D_IN    128
#define D_OUT   32
#define RPB     8                       // rows per fine bucket
#define NB      (N_NODES / RPB)         // 12500 fine buckets (exact)
#define CROWS   2048                    // rows per coarse bucket
#define NCB     49                      // ceil(100000/2048)
#define FPC     (CROWS / RPB)           // 256 fine buckets per coarse
#define NSH     8                       // shards per coarse
#define CAP_A   4500                    // records per (coarse,shard) seg
#define DEPTH   48                      // LDS staging depth per bin (mean 16, +8s)
#define CAPF    200                     // records per fine bucket (mean 128, +6s)
#define GRID_A  2048                    // 8 blocks/CU
#define EPB_A   ((N_EDGES + GRID_A - 1) / GRID_A)   // 782

typedef __attribute__((ext_vector_type(8))) short bf16x8;
typedef __attribute__((ext_vector_type(4))) float f32x4;

__device__ inline short f2bf(float f) {         // RNE float->bf16
    union { float f; unsigned u; } v; v.f = f;
    unsigned r = (v.u + 0x7FFFu + ((v.u >> 16) & 1u)) >> 16;
    return (short)r;
}
__device__ inline float bf2f(unsigned short b) {
    return __uint_as_float((unsigned)b << 16);
}

// ---------------------------------------------------------------------------
// W [128][32] fp32  ->  WbT [32][128] bf16
// ---------------------------------------------------------------------------
__global__ __launch_bounds__(256) void wconv_kernel(
    const float* __restrict__ W, short* __restrict__ WbT)
{
    const int i = blockIdx.x * 256 + threadIdx.x;
    if (i >= D_IN * D_OUT) return;
    const int k = i >> 5, c = i & 31;
    WbT[c * D_IN + k] = f2bf(W[i]);
}

// ---------------------------------------------------------------------------
// h16 = bf16(relu(input @ W)) via mfma_f32_16x16x32_bf16 (unchanged).
// ---------------------------------------------------------------------------
__global__ __launch_bounds__(256) void gemm_mfma_kernel(
    const float* __restrict__ in, const short* __restrict__ WbT,
    unsigned short* __restrict__ h16)
{
    const int wave = threadIdx.x >> 6;
    const int lane = threadIdx.x & 63;
    const int r0   = blockIdx.x * 64 + wave * 16;
    const int c16  = lane & 15;
    const int quad = lane >> 4;

    int ra = r0 + c16;
    if (ra >= N_NODES) ra = N_NODES - 1;
    const float* arow = in + (size_t)ra * D_IN;

    f32x4 acc0 = {0.f, 0.f, 0.f, 0.f};
    f32x4 acc1 = {0.f, 0.f, 0.f, 0.f};

#pragma unroll
    for (int q = 0; q < 4; ++q) {
        const float* ap = arow + q * 32 + quad * 8;
        f32x4 a0 = *(const f32x4*)(ap);
        f32x4 a1 = *(const f32x4*)(ap + 4);
        bf16x8 af;
        af[0] = f2bf(a0.x); af[1] = f2bf(a0.y); af[2] = f2bf(a0.z); af[3] = f2bf(a0.w);
        af[4] = f2bf(a1.x); af[5] = f2bf(a1.y); af[6] = f2bf(a1.z); af[7] = f2bf(a1.w);
        bf16x8 b0 = *(const bf16x8*)(WbT + (c16)      * D_IN + q * 32 + quad * 8);
        bf16x8 b1 = *(const bf16x8*)(WbT + (c16 + 16) * D_IN + q * 32 + quad * 8);
        acc0 = __builtin_amdgcn_mfma_f32_16x16x32_bf16(af, b0, acc0, 0, 0, 0);
        acc1 = __builtin_amdgcn_mfma_f32_16x16x32_bf16(af, b1, acc1, 0, 0, 0);
    }

#pragma unroll
    for (int i = 0; i < 4; ++i) {
        const int rr = r0 + quad * 4 + i;
        if (rr < N_NODES) {
            h16[(size_t)rr * D_OUT + c16]      = (unsigned short)f2bf(fmaxf(acc0[i], 0.f));
            h16[(size_t)rr * D_OUT + c16 + 16] = (unsigned short)f2bf(fmaxf(acc1[i], 0.f));
        }
    }
}

// ---------------------------------------------------------------------------
// Phase A (round-9 structure): 2048 blocks, single end-of-block flush,
// parallel cursor bumps, lane-parallel copies. Record: x = col | crl<<17
// (crl = row within coarse, 11b), y = etime (dw1 lookup DEFERRED to reduce).
// ---------------------------------------------------------------------------
__global__ __launch_bounds__(256) void phaseA_kernel(
    const int* __restrict__ erow, const int* __restrict__ ecol,
    const int* __restrict__ etime,
    int* __restrict__ gcur,          // NCB*NSH cursors, stride 16 ints
    uint2* __restrict__ segA)
{
    __shared__ uint2 lbin[NCB][DEPTH];   // 18.8 KB
    __shared__ int   lcnt[NCB];
    __shared__ int   gbase[NCB];

    const int tid   = threadIdx.x;
    const int blk   = blockIdx.x;
    const int shard = blk & (NSH - 1);
    const int wv    = tid >> 6;
    const int ln    = tid & 63;

    if (tid < NCB) lcnt[tid] = 0;
    __syncthreads();

    const int e_beg = blk * EPB_A;
    const int e_end = min(e_beg + EPB_A, N_EDGES);

    for (int e = e_beg + tid; e < e_end; e += 256) {
        const int row = erow[e];
        const int cb  = row >> 11;
        uint2 p;
        p.x = (unsigned)ecol[e] | ((unsigned)(row & (CROWS - 1)) << 17);
        p.y = (unsigned)etime[e];
        const int pos = atomicAdd(&lcnt[cb], 1);
        if (pos < DEPTH) lbin[cb][pos] = p;
    }
    __syncthreads();

    if (tid < NCB) {
        const int c = min(lcnt[tid], DEPTH);
        gbase[tid] = atomicAdd(&gcur[(tid * NSH + shard) * 16], c);
    }
    __syncthreads();

    for (int bin = wv; bin < NCB; bin += 4) {
        const int c  = min(lcnt[bin], DEPTH);
        const int gb = gbase[bin];
        uint2* seg = segA + (size_t)(bin * NSH + shard) * CAP_A;
        for (int k = ln; k < c; k += 64) {
            if (gb + k < CAP_A) seg[gb + k] = lbin[bin][k];
        }
    }
}

// ---------------------------------------------------------------------------
// Phase B: 2 blocks per (coarse, shard) segment (784 blocks, ~3/CU).
// Packs to 4-byte fine records: col(17) | rl_fine(3)<<17 | etime(12)<<20.
// ---------------------------------------------------------------------------
__global__ __launch_bounds__(256) void phaseB_kernel(
    const int* __restrict__ gcur, const uint2* __restrict__ segA,
    int* __restrict__ fcur,
    unsigned* __restrict__ spk2)
{
    __shared__ int hist[FPC];   // 256 bins == blockDim
    __shared__ int curs[FPC];

    const int tid    = threadIdx.x;
    const int seg_id = blockIdx.x >> 1;
    const int half   = blockIdx.x & 1;
    const int cb     = seg_id >> 3;
    const int shard  = seg_id & 7;
    const int ntot   = min(gcur[(cb * NSH + shard) * 16], CAP_A);
    const int nh     = (ntot + 1) >> 1;
    const int beg    = half * nh;
    const int end    = min(ntot, beg + nh);
    const uint2* seg = segA + (size_t)(cb * NSH + shard) * CAP_A;

    hist[tid] = 0;
    __syncthreads();

    for (int i = beg + tid; i < end; i += 256)
        atomicAdd(&hist[(seg[i].x >> 20) & 255], 1);   // fl = crl>>3
    __syncthreads();

    {
        const int h  = hist[tid];
        const int fb = cb * FPC + tid;
        curs[tid] = (h && fb < NB) ? atomicAdd(&fcur[fb], h) : 0;
    }
    __syncthreads();

    for (int i = beg + tid; i < end; i += 256) {
        const uint2 p   = seg[i];
        const unsigned crl = (p.x >> 17) & 2047u;
        const int      fl  = crl >> 3;
        const unsigned rec = (p.x & 0x1FFFFu) | ((crl & 7u) << 17) | (p.y << 20);
        const int pos = atomicAdd(&curs[fl], 1);
        if (pos < CAPF)
            spk2[(size_t)(cb * FPC + fl) * CAPF + pos] = rec;
    }
}

// ---------------------------------------------------------------------------
// Bucket reduce: 12500 blocks, 4-byte records, dw1[etime] lookup (L1-hot
// 14.4 KB table). 8-bin rl counting sort in LDS -> register accumulation,
// 4 independent h16 gathers + 4 dw1 hits in flight; fused dw2 scale.
// ---------------------------------------------------------------------------
__global__ __launch_bounds__(256) void bucket_reduce_kernel(
    const unsigned short* __restrict__ h16, const int* __restrict__ fcur,
    const unsigned* __restrict__ spk2, const float* __restrict__ dw1,
    const float* __restrict__ dw2, const int* __restrict__ arrive,
    const int* __restrict__ obs, float* __restrict__ out)
{
    __shared__ unsigned pk[CAPF];        // 0.8 KB
    __shared__ unsigned pks[CAPF];       // 0.8 KB
    __shared__ int bin[RPB];
    __shared__ int start[RPB + 1];
    __shared__ int cur[RPB];

    const int tid = threadIdx.x;
    const int b   = blockIdx.x;
    const int n   = min(fcur[b], CAPF);
    const unsigned* seg = spk2 + (size_t)b * CAPF;

    if (tid < RPB) bin[tid] = 0;
    __syncthreads();

    for (int i = tid; i < n; i += 256) {
        const unsigned p = seg[i];
        pk[i] = p;
        atomicAdd(&bin[(p >> 17) & 7], 1);
    }
    __syncthreads();

    if (tid == 0) {
        int a = 0;
#pragma unroll
        for (int r = 0; r < RPB; ++r) { start[r] = a; cur[r] = a; a += bin[r]; }
        start[RPB] = a;
    }
    __syncthreads();

    for (int i = tid; i < n; i += 256) {
        const unsigned p = pk[i];
        pks[atomicAdd(&cur[(p >> 17) & 7], 1)] = p;
    }
    __syncthreads();

    const int c = tid & 31;
    const int g = tid >> 5;              // group g owns row g (RPB==8)
    const int T = 60 * obs[0];

    const int beg = start[g];
    const int end = start[g + 1];

    float acc = 0.f;
    int j = beg;
    for (; j + 4 <= end; j += 4) {
        const unsigned p0 = pks[j];
        const unsigned p1 = pks[j + 1];
        const unsigned p2 = pks[j + 2];
        const unsigned p3 = pks[j + 3];
        const float v0 = bf2f(h16[(size_t)(p0 & 0x1FFFF) * D_OUT + c]);
        const float v1 = bf2f(h16[(size_t)(p1 & 0x1FFFF) * D_OUT + c]);
        const float v2 = bf2f(h16[(size_t)(p2 & 0x1FFFF) * D_OUT + c]);
        const float v3 = bf2f(h16[(size_t)(p3 & 0x1FFFF) * D_OUT + c]);
        const float w0 = dw1[p0 >> 20];
        const float w1 = dw1[p1 >> 20];
        const float w2 = dw1[p2 >> 20];
        const float w3 = dw1[p3 >> 20];
        acc = fmaf(w0, v0, acc);
        acc = fmaf(w1, v1, acc);
        acc = fmaf(w2, v2, acc);
        acc = fmaf(w3, v3, acc);
    }
    for (; j < end; ++j) {
        const unsigned p = pks[j];
        acc = fmaf(dw1[p >> 20],
                   bf2f(h16[(size_t)(p & 0x1FFFF) * D_OUT + c]), acc);
    }

    const int r = b * RPB + g;           // 12500*8 = 100000 exact
    const float sdw = dw2[T - arrive[r] - 1];
    out[(size_t)r * D_OUT + c] = acc * sdw;
}

extern "C" void kernel_launch(void* const* d_in, const int* in_sizes, int n_in,
                              void* d_out, int out_size, void* d_ws, size_t ws_size,
                              hipStream_t stream)
{
    const float* input  = (const float*)d_in[0];
    const float* W      = (const float*)d_in[1];
    const float* dw1    = (const float*)d_in[2];
    const float* dw2    = (const float*)d_in[3];
    const int*   erow   = (const int*)d_in[4];
    const int*   ecol   = (const int*)d_in[5];
    const int*   etime  = (const int*)d_in[6];
    const int*   arrive = (const int*)d_in[7];
    const int*   obs    = (const int*)d_in[8];

    float* out = (float*)d_out;

    // Workspace layout (~31 MB), 256B-aligned chunks
    char* p = (char*)d_ws;
    unsigned short* h16 = (unsigned short*)p;                 // 6.4 MB
    p += (size_t)N_NODES * D_OUT * 2;
    p = (char*)(((size_t)p + 255) & ~(size_t)255);
    short* WbT = (short*)p;                                   // 8 KB
    p += D_IN * D_OUT * 2;
    p = (char*)(((size_t)p + 255) & ~(size_t)255);
    int* gcur = (int*)p;                                      // 25 KB
    p += (size_t)NCB * NSH * 16 * 4;
    int* fcur = (int*)p;                                      // 50 KB (adjacent to gcur)
    p += (size_t)NB * 4;
    p = (char*)(((size_t)p + 255) & ~(size_t)255);
    uint2* segA = (uint2*)p;                                  // 14.1 MB
    p += (size_t)NCB * NSH * CAP_A * 8;
    p = (char*)(((size_t)p + 255) & ~(size_t)255);
    unsigned* spk2 = (unsigned*)p;                            // 10 MB

    hipMemsetAsync(gcur, 0, (size_t)(NCB * NSH * 16 + NB) * 4, stream);

    wconv_kernel<<<(D_IN * D_OUT + 255) / 256, 256, 0, stream>>>(W, WbT);
    gemm_mfma_kernel<<<(N_NODES + 63) / 64, 256, 0, stream>>>(input, WbT, h16);
    phaseA_kernel<<<GRID_A, 256, 0, stream>>>(erow, ecol, etime, gcur, segA);
    phaseB_kernel<<<NCB * NSH * 2, 256, 0, stream>>>(gcur, segA, fcur, spk2);
    bucket_reduce_kernel<<<NB, 256, 0, stream>>>(
        h16, fcur, spk2, dw1, dw2, arrive, obs, out);
}

// Round 12
// 184.251 us; speedup vs baseline: 1.2642x; 1.0025x over previous
//
#include <hip/hip_runtime.h>

#define N_NODES 100000
#define N_EDGES 1600000
#define D_IN    128
#define D_OUT   32
#define RPB     8                       // rows per fine bucket
#define NB      (N_NODES / RPB)         // 12500 fine buckets (exact)
#define CROWS   2048                    // rows per coarse bucket
#define NCB     49                      // ceil(100000/2048)
#define FPC     (CROWS / RPB)           // 256 fine buckets per coarse
#define NSH     8                       // shards per coarse
#define CAP_A   4500                    // records per (coarse,shard) seg
#define DEPTH   48                      // LDS staging depth per bin (mean 16, +8s)
#define CAPF    200                     // records per fine bucket (mean 128, +6s)
#define GEMM_BLKS ((N_NODES + 63) / 64) // 1563
#define GRID_A  2048                    // phaseA blocks (8/CU when alone)
#define EPB_A   ((N_EDGES + GRID_A - 1) / GRID_A)   // 782

typedef __attribute__((ext_vector_type(8))) short bf16x8;
typedef __attribute__((ext_vector_type(4))) float f32x4;

__device__ inline short f2bf(float f) {         // RNE float->bf16
    union { float f; unsigned u; } v; v.f = f;
    unsigned r = (v.u + 0x7FFFu + ((v.u >> 16) & 1u)) >> 16;
    return (short)r;
}
__device__ inline float bf2f(unsigned short b) {
    return __uint_as_float((unsigned)b << 16);
}

// ---------------------------------------------------------------------------
// Combined kernel: blocks [0, GEMM_BLKS) do gemm (W converted into LDS per
// block -- kills the wconv dispatch); blocks [GEMM_BLKS, +GRID_A) do phaseA.
// The two roles are data-independent and co-execute, hiding each other's
// latency (MFMA waves + LDS/atomic waves co-schedule per m114).
// ---------------------------------------------------------------------------
union SMemGA {
    struct { short wbt[D_IN * D_OUT]; } g;                               // 8 KB
    struct { uint2 lbin[NCB][DEPTH]; int lcnt[NCB]; int gbase[NCB]; } a; // 19.2 KB
};

__global__ __launch_bounds__(256) void gemm_phaseA_kernel(
    const float* __restrict__ input, const float* __restrict__ W,
    const int* __restrict__ erow,    const int* __restrict__ ecol,
    const int* __restrict__ etime,
    unsigned short* __restrict__ h16,
    int* __restrict__ gcur,          // NCB*NSH cursors, stride 16 ints
    uint2* __restrict__ segA)
{
    __shared__ SMemGA sm;
    const int tid = threadIdx.x;

    if (blockIdx.x < GEMM_BLKS) {
        // ----------------- gemm role: h16 = bf16(relu(in @ W)) ------------
        for (int i = tid; i < D_IN * D_OUT; i += 256) {
            const int k = i >> 5, c = i & 31;
            sm.g.wbt[c * D_IN + k] = f2bf(W[i]);
        }
        __syncthreads();

        const int wave = tid >> 6;
        const int lane = tid & 63;
        const int r0   = blockIdx.x * 64 + wave * 16;
        const int c16  = lane & 15;
        const int quad = lane >> 4;

        int ra = r0 + c16;
        if (ra >= N_NODES) ra = N_NODES - 1;
        const float* arow = input + (size_t)ra * D_IN;

        f32x4 acc0 = {0.f, 0.f, 0.f, 0.f};
        f32x4 acc1 = {0.f, 0.f, 0.f, 0.f};
#pragma unroll
        for (int q = 0; q < 4; ++q) {
            const float* ap = arow + q * 32 + quad * 8;
            f32x4 a0 = *(const f32x4*)(ap);
            f32x4 a1 = *(const f32x4*)(ap + 4);
            bf16x8 af;
            af[0] = f2bf(a0.x); af[1] = f2bf(a0.y); af[2] = f2bf(a0.z); af[3] = f2bf(a0.w);
            af[4] = f2bf(a1.x); af[5] = f2bf(a1.y); af[6] = f2bf(a1.z); af[7] = f2bf(a1.w);
            bf16x8 b0 = *(const bf16x8*)(sm.g.wbt + (c16)      * D_IN + q * 32 + quad * 8);
            bf16x8 b1 = *(const bf16x8*)(sm.g.wbt + (c16 + 16) * D_IN + q * 32 + quad * 8);
            acc0 = __builtin_amdgcn_mfma_f32_16x16x32_bf16(af, b0, acc0, 0, 0, 0);
            acc1 = __builtin_amdgcn_mfma_f32_16x16x32_bf16(af, b1, acc1, 0, 0, 0);
        }
#pragma unroll
        for (int i = 0; i < 4; ++i) {
            const int rr = r0 + quad * 4 + i;
            if (rr < N_NODES) {
                h16[(size_t)rr * D_OUT + c16]      = (unsigned short)f2bf(fmaxf(acc0[i], 0.f));
                h16[(size_t)rr * D_OUT + c16 + 16] = (unsigned short)f2bf(fmaxf(acc1[i], 0.f));
            }
        }
    } else {
        // ----------------- phaseA role: coarse partition ------------------
        const int blk   = blockIdx.x - GEMM_BLKS;
        const int shard = blk & (NSH - 1);
        const int wv    = tid >> 6;
        const int ln    = tid & 63;

        if (tid < NCB) sm.a.lcnt[tid] = 0;
        __syncthreads();

        const int e_beg = blk * EPB_A;
        const int e_end = min(e_beg + EPB_A, N_EDGES);

        for (int e = e_beg + tid; e < e_end; e += 256) {
            const int row = erow[e];
            const int cb  = row >> 11;
            uint2 p;
            p.x = (unsigned)ecol[e] | ((unsigned)(row & (CROWS - 1)) << 17);
            p.y = (unsigned)etime[e];
            const int pos = atomicAdd(&sm.a.lcnt[cb], 1);
            if (pos < DEPTH) sm.a.lbin[cb][pos] = p;
            else {  // statistically never; correctness-safe direct write
                const int gp = atomicAdd(&gcur[(cb * NSH + shard) * 16], 1);
                if (gp < CAP_A) segA[(size_t)(cb * NSH + shard) * CAP_A + gp] = p;
            }
        }
        __syncthreads();

        if (tid < NCB) {
            const int c = min(sm.a.lcnt[tid], DEPTH);
            sm.a.gbase[tid] = atomicAdd(&gcur[(tid * NSH + shard) * 16], c);
        }
        __syncthreads();

        for (int bin = wv; bin < NCB; bin += 4) {
            const int c  = min(sm.a.lcnt[bin], DEPTH);
            const int gb = sm.a.gbase[bin];
            uint2* seg = segA + (size_t)(bin * NSH + shard) * CAP_A;
            for (int k = ln; k < c; k += 64)
                if (gb + k < CAP_A) seg[gb + k] = sm.a.lbin[bin][k];
        }
    }
}

// ---------------------------------------------------------------------------
// Phase B: 2 blocks per (coarse, shard) segment (784 blocks).
// Packs to 4-byte fine records: col(17) | rl_fine(3)<<17 | etime(12)<<20.
// ---------------------------------------------------------------------------
__global__ __launch_bounds__(256) void phaseB_kernel(
    const int* __restrict__ gcur, const uint2* __restrict__ segA,
    int* __restrict__ fcur,
    unsigned* __restrict__ spk2)
{
    __shared__ int hist[FPC];
    __shared__ int curs[FPC];

    const int tid    = threadIdx.x;
    const int seg_id = blockIdx.x >> 1;
    const int half   = blockIdx.x & 1;
    const int cb     = seg_id >> 3;
    const int shard  = seg_id & 7;
    const int ntot   = min(gcur[(cb * NSH + shard) * 16], CAP_A);
    const int nh     = (ntot + 1) >> 1;
    const int beg    = half * nh;
    const int end    = min(ntot, beg + nh);
    const uint2* seg = segA + (size_t)(cb * NSH + shard) * CAP_A;

    hist[tid] = 0;
    __syncthreads();

    for (int i = beg + tid; i < end; i += 256)
        atomicAdd(&hist[(seg[i].x >> 20) & 255], 1);
    __syncthreads();

    {
        const int h  = hist[tid];
        const int fb = cb * FPC + tid;
        curs[tid] = (h && fb < NB) ? atomicAdd(&fcur[fb], h) : 0;
    }
    __syncthreads();

    for (int i = beg + tid; i < end; i += 256) {
        const uint2 p   = seg[i];
        const unsigned crl = (p.x >> 17) & 2047u;
        const int      fl  = crl >> 3;
        const unsigned rec = (p.x & 0x1FFFFu) | ((crl & 7u) << 17) | (p.y << 20);
        const int pos = atomicAdd(&curs[fl], 1);
        if (pos < CAPF)
            spk2[(size_t)(cb * FPC + fl) * CAPF + pos] = rec;
    }
}

// ---------------------------------------------------------------------------
// Bucket reduce: 12500 blocks, 4B records, dw1[etime] L1 lookups, 8-bin
// LDS counting sort, register accumulation with 8 independent gathers.
// ---------------------------------------------------------------------------
__global__ __launch_bounds__(256) void bucket_reduce_kernel(
    const unsigned short* __restrict__ h16, const int* __restrict__ fcur,
    const unsigned* __restrict__ spk2, const float* __restrict__ dw1,
    const float* __restrict__ dw2, const int* __restrict__ arrive,
    const int* __restrict__ obs, float* __restrict__ out)
{
    __shared__ unsigned pk[CAPF];
    __shared__ unsigned pks[CAPF];
    __shared__ int bin[RPB];
    __shared__ int start[RPB + 1];
    __shared__ int cur[RPB];

    const int tid = threadIdx.x;
    const int b   = blockIdx.x;
    const int n   = min(fcur[b], CAPF);
    const unsigned* seg = spk2 + (size_t)b * CAPF;

    if (tid < RPB) bin[tid] = 0;
    __syncthreads();

    for (int i = tid; i < n; i += 256) {
        const unsigned p = seg[i];
        pk[i] = p;
        atomicAdd(&bin[(p >> 17) & 7], 1);
    }
    __syncthreads();

    if (tid == 0) {
        int a = 0;
#pragma unroll
        for (int r = 0; r < RPB; ++r) { start[r] = a; cur[r] = a; a += bin[r]; }
        start[RPB] = a;
    }
    __syncthreads();

    for (int i = tid; i < n; i += 256) {
        const unsigned p = pk[i];
        pks[atomicAdd(&cur[(p >> 17) & 7], 1)] = p;
    }
    __syncthreads();

    const int c = tid & 31;
    const int g = tid >> 5;              // group g owns row g (RPB==8)
    const int T = 60 * obs[0];

    const int beg = start[g];
    const int end = start[g + 1];

    float acc = 0.f;
    int j = beg;
    for (; j + 8 <= end; j += 8) {
        float a0 = 0.f, a1 = 0.f;
#pragma unroll
        for (int u = 0; u < 8; u += 2) {
            const unsigned pa = pks[j + u];
            const unsigned pb = pks[j + u + 1];
            const float va = bf2f(h16[(size_t)(pa & 0x1FFFF) * D_OUT + c]);
            const float vb = bf2f(h16[(size_t)(pb & 0x1FFFF) * D_OUT + c]);
            a0 = fmaf(dw1[pa >> 20], va, a0);
            a1 = fmaf(dw1[pb >> 20], vb, a1);
        }
        acc += a0 + a1;
    }
    for (; j < end; ++j) {
        const unsigned p = pks[j];
        acc = fmaf(dw1[p >> 20],
                   bf2f(h16[(size_t)(p & 0x1FFFF) * D_OUT + c]), acc);
    }

    const int r = b * RPB + g;           // 12500*8 = 100000 exact
    const float sdw = dw2[T - arrive[r] - 1];
    out[(size_t)r * D_OUT + c] = acc * sdw;
}

extern "C" void kernel_launch(void* const* d_in, const int* in_sizes, int n_in,
                              void* d_out, int out_size, void* d_ws, size_t ws_size,
                              hipStream_t stream)
{
    const float* input  = (const float*)d_in[0];
    const float* W      = (const float*)d_in[1];
    const float* dw1    = (const float*)d_in[2];
    const float* dw2    = (const float*)d_in[3];
    const int*   erow   = (const int*)d_in[4];
    const int*   ecol   = (const int*)d_in[5];
    const int*   etime  = (const int*)d_in[6];
    const int*   arrive = (const int*)d_in[7];
    const int*   obs    = (const int*)d_in[8];

    float* out = (float*)d_out;

    // Workspace layout (~31 MB); gcur and fcur contiguous for one memset
    char* p = (char*)d_ws;
    unsigned short* h16 = (unsigned short*)p;                 // 6.4 MB
    p += (size_t)N_NODES * D_OUT * 2;
    p = (char*)(((size_t)p + 255) & ~(size_t)255);
    int* gcur = (int*)p;                                      // 25 KB
    p += (size_t)NCB * NSH * 16 * 4;
    int* fcur = (int*)p;                                      // 50 KB
    p += (size_t)NB * 4;
    p = (char*)(((size_t)p + 255) & ~(size_t)255);
    uint2* segA = (uint2*)p;                                  // 14.1 MB
    p += (size_t)NCB * NSH * CAP_A * 8;
    p = (char*)(((size_t)p + 255) & ~(size_t)255);
    unsigned* spk2 = (unsigned*)p;                            // 10 MB

    hipMemsetAsync(gcur, 0, (size_t)(NCB * NSH * 16 + NB) * 4, stream);

    gemm_phaseA_kernel<<<GEMM_BLKS + GRID_A, 256, 0, stream>>>(
        input, W, erow, ecol, etime, h16, gcur, segA);
    phaseB_kernel<<<NCB * NSH * 2, 256, 0, stream>>>(gcur, segA, fcur, spk2);
    bucket_reduce_kernel<<<NB, 256, 0, stream>>>(
        h16, fcur, spk2, dw1, dw2, arrive, obs, out);
}